// Round 1
// baseline (122.988 us; speedup 1.0000x reference)
//
#include <hip/hip_runtime.h>

// BayesLinearEMP: out[b,o] = dot(W[mode[b],o,:], x[b,:]) + bias[mode[b],o]
// B=128, I=O=2048, M=20, fp32. Memory-bound on the 335 MB weight tensor.
// Strategy: group samples by mode (on device), then stream each weight row
// exactly once, fanning it out to all samples sharing that mode.

#define M_MODES 20
#define B_SAMP  128
#define I_DIM   2048
#define O_DIM   2048
#define SMAX    16            // samples per pass (acc regs = 4*16 = 64)
#define RPW     4             // output rows per wave
#define WPB     4             // waves per block
#define ROWS_PER_BLOCK (RPW * WPB)          // 16
#define OTILES  (O_DIM / ROWS_PER_BLOCK)    // 128

// ---- kernel 1: bucket samples by mode --------------------------------------
__global__ void group_kernel(const int* __restrict__ mode_idx,
                             int* __restrict__ counts,
                             int* __restrict__ lists) {
    __shared__ int cnt[M_MODES];
    const int tid = threadIdx.x;
    if (tid < M_MODES) cnt[tid] = 0;
    __syncthreads();
    if (tid < B_SAMP) {
        const int m = mode_idx[tid];
        const int pos = atomicAdd(&cnt[m], 1);
        lists[m * B_SAMP + pos] = tid;   // order within mode irrelevant
    }
    __syncthreads();
    if (tid < M_MODES) counts[tid] = cnt[tid];
}

// ---- kernel 2: grouped batched matvec --------------------------------------
__global__ __launch_bounds__(256, 2)
void bmv_kernel(const float* __restrict__ x,
                const float* __restrict__ weights,
                const float* __restrict__ biases,
                const int*   __restrict__ counts,
                const int*   __restrict__ lists,
                float*       __restrict__ out) {
    const int m  = blockIdx.x / OTILES;
    const int ot = blockIdx.x % OTILES;
    const int cnt = counts[m];
    if (cnt == 0) return;                 // unused mode: nothing to do

    const int tid  = threadIdx.x;
    const int wv   = tid >> 6;            // wave id 0..3
    const int lane = tid & 63;
    const int o0   = ot * ROWS_PER_BLOCK + wv * RPW;

    const float* wrow = weights + ((size_t)m * O_DIM + o0) * I_DIM;

    for (int s0 = 0; s0 < cnt; s0 += SMAX) {
        const int scount = min(cnt - s0, SMAX);   // wave-uniform

        int sb[SMAX];
        #pragma unroll
        for (int s = 0; s < SMAX; ++s)
            sb[s] = (s < scount) ? lists[m * B_SAMP + s0 + s] : 0;

        float acc[RPW][SMAX];
        #pragma unroll
        for (int r = 0; r < RPW; ++r)
            #pragma unroll
            for (int s = 0; s < SMAX; ++s)
                acc[r][s] = 0.0f;

        // stream I in 256-float chunks: lane l owns float4 at i = c*256 + l*4
        for (int i = lane * 4; i < I_DIM; i += 256) {
            float4 w4[RPW];
            #pragma unroll
            for (int r = 0; r < RPW; ++r)
                w4[r] = *reinterpret_cast<const float4*>(wrow + (size_t)r * I_DIM + i);

            #pragma unroll
            for (int s = 0; s < SMAX; ++s) {
                if (s < scount) {         // uniform branch; keeps acc index static
                    const float4 xv =
                        *reinterpret_cast<const float4*>(x + (size_t)sb[s] * I_DIM + i);
                    #pragma unroll
                    for (int r = 0; r < RPW; ++r)
                        acc[r][s] += w4[r].x * xv.x + w4[r].y * xv.y
                                   + w4[r].z * xv.z + w4[r].w * xv.w;
                }
            }
        }

        // 64-lane reduction per (row, sample), then write out + bias
        #pragma unroll
        for (int r = 0; r < RPW; ++r) {
            const float bias = biases[(size_t)m * O_DIM + o0 + r];
            #pragma unroll
            for (int s = 0; s < SMAX; ++s) {
                if (s < scount) {
                    float v = acc[r][s];
                    #pragma unroll
                    for (int off = 32; off > 0; off >>= 1)
                        v += __shfl_xor(v, off, 64);
                    if (lane == 0)
                        out[(size_t)sb[s] * O_DIM + (o0 + r)] = v + bias;
                }
            }
        }
    }
}

extern "C" void kernel_launch(void* const* d_in, const int* in_sizes, int n_in,
                              void* d_out, int out_size, void* d_ws, size_t ws_size,
                              hipStream_t stream) {
    const float* x        = (const float*)d_in[0];
    const float* weights  = (const float*)d_in[1];
    const float* biases   = (const float*)d_in[2];
    const int*   mode_idx = (const int*)d_in[3];
    float* out = (float*)d_out;

    int* counts = (int*)d_ws;            // M ints
    int* lists  = counts + M_MODES;      // M*B ints

    group_kernel<<<1, 128, 0, stream>>>(mode_idx, counts, lists);
    bmv_kernel<<<M_MODES * OTILES, 256, 0, stream>>>(x, weights, biases,
                                                     counts, lists, out);
}

// Round 2
// 81.768 us; speedup vs baseline: 1.5041x; 1.5041x over previous
//
#include <hip/hip_runtime.h>

// BayesLinearEMP: out[b,o] = dot(W[mode[b],o,:], x[b,:]) + bias[mode[b],o]
// B=128, I=O=2048, M=20, fp32. Memory-bound: 335 MB weight stream (floor ~53us).
// Strategy: group samples by mode on device; each block owns (mode, 16-row
// O-tile) and streams weights exactly once, branch-free, fanning each weight
// row out to all samples of that mode.

#define M_MODES 20
#define B_SAMP  128
#define I_DIM   2048
#define O_DIM   2048
#define RPW     4             // output rows per wave
#define ROWS_PER_BLOCK 16     // 4 waves * RPW
#define OTILES  (O_DIM / ROWS_PER_BLOCK)    // 128

typedef float f32x4 __attribute__((ext_vector_type(4)));

// ---- kernel 1: bucket samples by mode --------------------------------------
__global__ void group_kernel(const int* __restrict__ mode_idx,
                             int* __restrict__ counts,
                             int* __restrict__ lists) {
    __shared__ int cnt[M_MODES];
    const int tid = threadIdx.x;
    if (tid < M_MODES) cnt[tid] = 0;
    __syncthreads();
    if (tid < B_SAMP) {
        const int m = mode_idx[tid];
        const int pos = atomicAdd(&cnt[m], 1);
        lists[m * B_SAMP + pos] = tid;
    }
    __syncthreads();
    if (tid < M_MODES) counts[tid] = cnt[tid];
}

// ---- x-load + FMA for a sub-group of <=8 samples (bounds live VGPRs) -------
template<int SC, int S0>
__device__ __forceinline__ void fma8(const float* const (&xb)[SC], int i,
                                     const f32x4 (&w4)[RPW],
                                     float (&acc)[RPW][SC]) {
    constexpr int G = (SC - S0) < 8 ? (SC - S0) : 8;
    f32x4 xv[G];
    #pragma unroll
    for (int s = 0; s < G; ++s)
        xv[s] = *reinterpret_cast<const f32x4*>(xb[S0 + s] + i);
    #pragma unroll
    for (int s = 0; s < G; ++s)
        #pragma unroll
        for (int r = 0; r < RPW; ++r)
            acc[r][S0 + s] += w4[r][0] * xv[s][0] + w4[r][1] * xv[s][1]
                            + w4[r][2] * xv[s][2] + w4[r][3] * xv[s][3];
}

// ---- branch-free body for SC samples (SC compile-time power of 2) ----------
template<int SC>
__device__ __forceinline__ void bmv_body(const float* __restrict__ x,
                                         const float* __restrict__ wrow,
                                         const float* __restrict__ biases,
                                         const int*   __restrict__ list,
                                         int scount, int m, int o0, int lane,
                                         float* __restrict__ out) {
    // wave-uniform x row bases -> SGPRs
    const float* xb[SC];
    #pragma unroll
    for (int s = 0; s < SC; ++s) {
        const int ss  = (s < scount) ? s : (scount - 1);   // clamp padding
        int idx = list[ss];
        idx = __builtin_amdgcn_readfirstlane(idx);
        xb[s] = x + (size_t)idx * I_DIM;
    }

    float acc[RPW][SC];
    #pragma unroll
    for (int r = 0; r < RPW; ++r)
        #pragma unroll
        for (int s = 0; s < SC; ++s)
            acc[r][s] = 0.0f;

    // stream I in 256-float chunks: lane l owns float4 at i = c*256 + l*4
    for (int i = lane * 4; i < I_DIM; i += 256) {
        f32x4 w4[RPW];
        #pragma unroll
        for (int r = 0; r < RPW; ++r)
            w4[r] = __builtin_nontemporal_load(
                reinterpret_cast<const f32x4*>(wrow + (size_t)r * I_DIM + i));
        fma8<SC, 0>(xb, i, w4, acc);
        if constexpr (SC > 8) fma8<SC, 8>(xb, i, w4, acc);
    }

    // merge-tree reduction: NV = RPW*SC values; each stage halves both the
    // live value count and the un-summed lane distance. Lane l ends holding
    // value j = l / (64/NV), fully reduced across all 64 lanes.
    constexpr int NV = RPW * SC;
    float v[NV];
    #pragma unroll
    for (int j = 0; j < NV; ++j)
        v[j] = acc[j & (RPW - 1)][j >> 2];     // j = s*4 + r
    int D = 32;
    #pragma unroll
    for (int n = NV; n > 1; n >>= 1, D >>= 1) {
        #pragma unroll
        for (int j = 0; j < n / 2; ++j) {
            const float a = v[j], b = v[j + n / 2];
            const bool hi = (lane & D) != 0;
            const float sel = hi ? b : a;
            const float oth = __shfl_xor(hi ? a : b, D, 64);
            v[j] = sel + oth;
        }
    }
    #pragma unroll
    for (int Dr = 64 / NV / 2; Dr >= 1; Dr >>= 1)   // residual butterfly (NV<64)
        v[0] += __shfl_xor(v[0], Dr, 64);

    // coalesced store: lane l -> value j = l/rep, j = s*4 + r
    constexpr int rep = 64 / NV;
    if ((lane & (rep - 1)) == 0) {
        const int j = lane / rep;
        const int s = j >> 2;
        const int r = j & (RPW - 1);
        if (s < scount) {
            const int idx = list[s];
            out[(size_t)idx * O_DIM + (o0 + r)] =
                v[0] + biases[(size_t)m * O_DIM + o0 + r];
        }
    }
}

// ---- kernel 2: grouped batched matvec --------------------------------------
__global__ __launch_bounds__(256, 3)
void bmv_kernel(const float* __restrict__ x,
                const float* __restrict__ weights,
                const float* __restrict__ biases,
                const int*   __restrict__ counts,
                const int*   __restrict__ lists,
                float*       __restrict__ out) {
    const int m  = blockIdx.x / OTILES;
    const int ot = blockIdx.x % OTILES;
    const int cnt = counts[m];
    if (cnt == 0) return;

    const int tid  = threadIdx.x;
    const int wv   = tid >> 6;
    const int lane = tid & 63;
    const int o0   = ot * ROWS_PER_BLOCK + wv * RPW;

    const float* wrow = weights + ((size_t)m * O_DIM + o0) * I_DIM;

    for (int s0 = 0; s0 < cnt; s0 += 16) {
        const int sc = min(cnt - s0, 16);
        const int* list = lists + m * B_SAMP + s0;
        if (sc > 8)
            bmv_body<16>(x, wrow, biases, list, sc, m, o0, lane, out);
        else if (sc > 4)
            bmv_body<8>(x, wrow, biases, list, sc, m, o0, lane, out);
        else if (sc > 2)
            bmv_body<4>(x, wrow, biases, list, sc, m, o0, lane, out);
        else if (sc == 2)
            bmv_body<2>(x, wrow, biases, list, sc, m, o0, lane, out);
        else
            bmv_body<1>(x, wrow, biases, list, sc, m, o0, lane, out);
    }
}

extern "C" void kernel_launch(void* const* d_in, const int* in_sizes, int n_in,
                              void* d_out, int out_size, void* d_ws, size_t ws_size,
                              hipStream_t stream) {
    const float* x        = (const float*)d_in[0];
    const float* weights  = (const float*)d_in[1];
    const float* biases   = (const float*)d_in[2];
    const int*   mode_idx = (const int*)d_in[3];
    float* out = (float*)d_out;

    int* counts = (int*)d_ws;            // M ints
    int* lists  = counts + M_MODES;      // M*B ints

    group_kernel<<<1, 128, 0, stream>>>(mode_idx, counts, lists);
    bmv_kernel<<<M_MODES * OTILES, 256, 0, stream>>>(x, weights, biases,
                                                     counts, lists, out);
}